// Round 1
// baseline (524.604 us; speedup 1.0000x reference)
//
#include <hip/hip_runtime.h>

#define HW 16384
#define NQ 300
#define NM 100
#define NB 8
#define NC 81
#define KCH 1024   // K split into 16 chunks
#define NKC 16
#define CTP 304    // padded leading dim for transposed cost

typedef __attribute__((ext_vector_type(8))) short frag8;
typedef __attribute__((ext_vector_type(4))) float float4v;
typedef __attribute__((ext_vector_type(4))) unsigned short ushort4v;

__device__ __forceinline__ unsigned short f2bf(float f) {
  union { float f; unsigned u; } c; c.f = f;
  unsigned r = c.u + 0x7FFFu + ((c.u >> 16) & 1u);
  return (unsigned short)(r >> 16);
}

// ---- prep: sigmoid(pred_masks)->bf16 + row sums; gt_masks->bf16 + row sums ----
__global__ __launch_bounds__(256) void prep_kernel(
    const float* __restrict__ pmask, const float* __restrict__ gmask,
    unsigned short* __restrict__ pm, unsigned short* __restrict__ gm,
    float* __restrict__ psum, float* __restrict__ gsum) {
  int row = blockIdx.x;            // 0..2399 = pm rows, 2400..3199 = gm rows
  int t = threadIdx.x;
  bool isP = row < NB * NQ;
  const float* srcf = isP ? (pmask + (size_t)row * HW)
                          : (gmask + (size_t)(row - NB * NQ) * HW);
  unsigned short* dst = isP ? (pm + (size_t)row * HW)
                            : (gm + (size_t)(row - NB * NQ) * HW);
  const float4v* src = (const float4v*)srcf;
  float s = 0.f;
  for (int i = t; i < HW / 4; i += 256) {
    float4v x = src[i];
    float y0, y1, y2, y3;
    if (isP) {
      y0 = 1.f / (1.f + __expf(-x.x));
      y1 = 1.f / (1.f + __expf(-x.y));
      y2 = 1.f / (1.f + __expf(-x.z));
      y3 = 1.f / (1.f + __expf(-x.w));
    } else { y0 = x.x; y1 = x.y; y2 = x.z; y3 = x.w; }
    s += (y0 + y1) + (y2 + y3);
    ushort4v o = { f2bf(y0), f2bf(y1), f2bf(y2), f2bf(y3) };
    *(ushort4v*)(dst + i * 4) = o;
  }
  for (int off = 32; off > 0; off >>= 1) s += __shfl_xor(s, off, 64);
  __shared__ float red[4];
  int wave = t >> 6, lane = t & 63;
  if (lane == 0) red[wave] = s;
  __syncthreads();
  if (t == 0) {
    float tot = (red[0] + red[1]) + (red[2] + red[3]);
    if (isP) psum[row] = tot; else gsum[row - NB * NQ] = tot;
  }
}

// ---- softmax over 81 classes, one wave per (b,q) row ----
__global__ __launch_bounds__(256) void softmax_kernel(
    const float* __restrict__ logits, float* __restrict__ probs) {
  int wave = threadIdx.x >> 6, lane = threadIdx.x & 63;
  int row = blockIdx.x * 4 + wave;          // < 2400 (grid=600)
  const float* in = logits + (size_t)row * NC;
  float x0 = (lane < NC) ? in[lane] : -1e30f;
  float x1 = (lane + 64 < NC) ? in[lane + 64] : -1e30f;
  float mx = fmaxf(x0, x1);
  for (int off = 32; off > 0; off >>= 1) mx = fmaxf(mx, __shfl_xor(mx, off, 64));
  float e0 = (lane < NC) ? __expf(x0 - mx) : 0.f;
  float e1 = (lane + 64 < NC) ? __expf(x1 - mx) : 0.f;
  float s = e0 + e1;
  for (int off = 32; off > 0; off >>= 1) s += __shfl_xor(s, off, 64);
  float inv = 1.f / s;
  if (lane < NC) probs[(size_t)row * NC + lane] = e0 * inv;
  if (lane + 64 < NC) probs[(size_t)row * NC + lane + 64] = e1 * inv;
}

// ---- bf16 MFMA batched GEMM: dot[b,q,m] accumulated via fp32 atomics ----
// One wave per (16-q tile, b, kc of 16); 2432 waves => ~9.5 waves/CU.
__global__ __launch_bounds__(64) void dot_kernel(
    const unsigned short* __restrict__ pm, const unsigned short* __restrict__ gm,
    float* __restrict__ dotv) {
  int qt = blockIdx.x;                      // 0..18 (16-q tiles)
  int b = blockIdx.y >> 4, kc = blockIdx.y & 15;
  int lane = threadIdx.x;
  int q0 = qt * 16;
  int row_a = q0 + (lane & 15);
  int ra = (row_a < NQ) ? row_a : NQ - 1;   // clamp; clamped rows never stored
  int koff = (lane >> 4) * 8;
  const unsigned short* pA = pm + ((size_t)b * NQ + ra) * HW + kc * KCH + koff;
  const unsigned short* pB0 = gm + (size_t)b * NM * HW + kc * KCH + koff;
  const unsigned short* pB[7];
#pragma unroll
  for (int mt = 0; mt < 7; ++mt) {
    int row_b = mt * 16 + (lane & 15);
    int rb = (row_b < NM) ? row_b : NM - 1;
    pB[mt] = pB0 + (size_t)rb * HW;
  }
  float4v acc[7];
#pragma unroll
  for (int mt = 0; mt < 7; ++mt) acc[mt] = (float4v){0.f, 0.f, 0.f, 0.f};
#pragma unroll 2
  for (int k = 0; k < KCH; k += 32) {
    frag8 a = *(const frag8*)(pA + k);
#pragma unroll
    for (int mt = 0; mt < 7; ++mt) {
      frag8 bb = *(const frag8*)(pB[mt] + k);
      acc[mt] = __builtin_amdgcn_mfma_f32_16x16x32_bf16(a, bb, acc[mt], 0, 0, 0);
    }
  }
  // C/D layout: col = lane&15 (m), row = (lane>>4)*4 + r (q)
#pragma unroll
  for (int mt = 0; mt < 7; ++mt) {
    int cm = mt * 16 + (lane & 15);
    if (cm < NM) {
#pragma unroll
      for (int r = 0; r < 4; ++r) {
        int cq = q0 + (lane >> 4) * 4 + r;
        if (cq < NQ)
          unsafeAtomicAdd(&dotv[((size_t)b * NQ + cq) * NM + cm], acc[mt][r]);
      }
    }
  }
}

// ---- combine all cost terms -> C (d_out) and transposed copy CT (ws) ----
__global__ __launch_bounds__(256) void combine_kernel(
    const float* __restrict__ dotv, const float* __restrict__ psum,
    const float* __restrict__ gsum, const float* __restrict__ probs,
    const int* __restrict__ labels, const float* __restrict__ pboxes,
    const float* __restrict__ gboxes, float* __restrict__ outC,
    float* __restrict__ ct) {
  int idx = blockIdx.x * 256 + threadIdx.x;
  if (idx >= NB * NQ * NM) return;
  int b = idx / (NQ * NM);
  int r = idx - b * (NQ * NM);
  int q = r / NM;
  int m = r - q * NM;
  float num = 2.f * dotv[idx];
  float den = psum[b * NQ + q] + gsum[b * NM + m];
  float cmask = 1.f - num / (den + 1e-6f);
  int lab = labels[b * NM + m];
  float cclass = -probs[((size_t)b * NQ + q) * NC + lab];
  const float* pb = pboxes + ((size_t)b * NQ + q) * 4;
  const float* gb = gboxes + ((size_t)b * NM + m) * 4;
  float p0 = pb[0], p1 = pb[1], p2 = pb[2], p3 = pb[3];
  float g0 = gb[0], g1 = gb[1], g2 = gb[2], g3 = gb[3];
  float cbbox = fabsf(p0 - g0) + fabsf(p1 - g1) + fabsf(p2 - g2) + fabsf(p3 - g3);
  float iw = fmaxf(fminf(p2, g2) - fmaxf(p0, g0), 0.f);
  float ih = fmaxf(fminf(p3, g3) - fmaxf(p1, g1), 0.f);
  float inter = iw * ih;
  float a1 = (p2 - p0) * (p3 - p1), a2 = (g2 - g0) * (g3 - g1);
  float uni = a1 + a2 - inter;
  float iou = inter / (uni + 1e-6f);
  float aw = fmaxf(fmaxf(p2, g2) - fminf(p0, g0), 0.f);
  float ah = fmaxf(fmaxf(p3, g3) - fminf(p1, g1), 0.f);
  float am = aw * ah;
  float giou = iou - (am - uni) / (am + 1e-6f);
  float C = cclass + 5.f * (cbbox - giou) + 2.f * cmask;
  outC[idx] = C;
  ct[((size_t)b * NM + m) * CTP + q] = C;   // transposed for the solver
}

// ---- Jonker-Volgenant on cost.T [100 x 300], one wave per batch ----
// v2 (latency rework of the proven e-maxx-equivalent solver):
//  * init: row reduction -> parallel greedy (LDS atomicMin: lowest row wins
//    its argmin column == serial ascending-i greedy) -> deterministic
//    ballot-prefix free-row queue (ascending).
//  * augmenting row reduction (JV'87): per free row, one wave-parallel
//    min1/min2 scan; set u[i]=m2, v[j1]-=(m2-m1) (keeps duals feasible,
//    new edge reduced cost 0), steal j1 if occupied (victim re-queued;
//    each steal strictly decreases v so no cycles; pop budget caps it).
//    Exact-tie-with-occupied rows are left free for SAP (no ping-pong).
//  * SAP in Dijkstra/lapjv form: d[j] kept absolute (d = S + c - u0 - v0),
//    algebraically the same selections/tie-breaks as e-maxx's decremented
//    minv, but all u/v updates applied ONCE at phase end:
//      u[i0]+=S;  used j: amt=S-d[j]; v[j]-=amt; u[p[j]]+=amt.
//    This deletes the per-iteration dual-update pass (dependent LDS RMW
//    chain + 2 wave barriers) from the critical path.
//  * emit via ballot prefix (replaces serial lane-0 300-col walk).
// Exactness: feasibility + complementary slackness invariants hold at every
// step (v only decreases; kicked rows are freed), so the SAP finish is the
// exact optimum. Assignment matches reference assuming unique optimum (same
// assumption as the previously-passing kernel).
extern __shared__ char hsmem[];
__global__ __launch_bounds__(64) void hungarian_kernel(
    const float* __restrict__ ct, float* __restrict__ out) {
  float* cost   = (float*)hsmem;                     // 100*304 f32 = 121600 B
  float* u      = (float*)(hsmem + 121600);          // 100 f32
  int*   p      = (int*)(hsmem + 122000);            // 320 int (col -> row)
  int*   way    = (int*)(hsmem + 123280);            // 320 int
  int*   colOwn = (int*)(hsmem + 124560);            // 320 int
  int*   rowUsed= (int*)(hsmem + 125840);            // 100 int
  int*   queue  = (int*)(hsmem + 126240);            // 400 int
  int*   qmisc  = (int*)(hsmem + 127840);            // 8 int: [0]=head [1]=tail
  const int b = blockIdx.x;
  const int lane = threadIdx.x;
  const float INF = __builtin_inff();

  // vectorized cost load: 121600 B as float4 (CTP=304 keeps rows 16B-aligned)
  {
    const float4v* a4 = (const float4v*)(ct + (size_t)b * NM * CTP);
    float4v* c4 = (float4v*)cost;
    for (int i = lane; i < NM * CTP / 4; i += 64) c4[i] = a4[i];
  }
#pragma unroll
  for (int w = 0; w < 5; ++w) {
    p[lane + 64 * w] = -1;
    colOwn[lane + 64 * w] = 0x7fffffff;
  }
  if (lane == 0) { qmisc[0] = 0; qmisc[1] = 0; }
  float v[5];
#pragma unroll
  for (int w = 0; w < 5; ++w) v[w] = 0.f;
  __syncthreads();

  // ---- row reduction: u[i] = min_j cost[i][j]; remember argmin col ----
  int rarg0 = 0, rarg1 = 0;
  {
    int i = lane;                 // rows 0..63
    float mv = INF; int cj = 0;
    for (int j = 0; j < NQ; ++j) {
      float c = cost[i * CTP + j];
      if (c < mv) { mv = c; cj = j; }
    }
    u[i] = mv; rarg0 = cj;
  }
  if (lane < NM - 64) {           // rows 64..99
    int i = lane + 64;
    float mv = INF; int cj = 0;
    for (int j = 0; j < NQ; ++j) {
      float c = cost[i * CTP + j];
      if (c < mv) { mv = c; cj = j; }
    }
    u[i] = mv; rarg1 = cj;
  }
  // ---- parallel greedy: lowest row index wins its argmin column ----
  atomicMin(&colOwn[rarg0], lane);
  if (lane < NM - 64) atomicMin(&colOwn[rarg1], lane + 64);
  __syncthreads();
  int free0 = 0, free1 = 0;
  {
    bool won = (colOwn[rarg0] == lane);
    if (won) p[rarg0] = lane;
    rowUsed[lane] = won ? 1 : 0;
    free0 = won ? 0 : 1;
  }
  if (lane < NM - 64) {
    bool won = (colOwn[rarg1] == lane + 64);
    if (won) p[rarg1] = lane + 64;
    rowUsed[lane + 64] = won ? 1 : 0;
    free1 = won ? 0 : 1;
  }
  // deterministic free-row queue, ascending row index
  {
    unsigned long long m0 = __ballot(free0 != 0);
    if (free0) queue[__popcll(m0 & ((1ull << lane) - 1ull))] = lane;
    int base = (int)__popcll(m0);
    unsigned long long m1 = __ballot(free1 != 0);
    if (free1) queue[base + (int)__popcll(m1 & ((1ull << lane) - 1ull))] = lane + 64;
    base += (int)__popcll(m1);
    if (lane == 0) qmisc[1] = base;
  }

  // ---- augmenting row reduction (budgeted) ----
  int pops = 0;
  while (true) {
    __syncthreads();
    int h = qmisc[0], t = qmisc[1];
    if (h >= t || pops >= 192) break;
    int i = queue[h];
    ++pops;
    if (lane == 0) qmisc[0] = h + 1;
    // wave-parallel min1 (value+col) and min2 (value) of cost[i][.] - v[.]
    float m1 = INF, m2 = INF; int jl = 0;
#pragma unroll
    for (int w = 0; w < 5; ++w) {
      int j = lane + 64 * w;
      float tt = (j < NQ) ? (cost[i * CTP + j] - v[w]) : INF;
      if (tt < m1) { m2 = m1; m1 = tt; jl = j; } else if (tt < m2) m2 = tt;
    }
    unsigned long long best;
    {
      unsigned sb = __float_as_uint(m1);
      sb = (sb >> 31) ? ~sb : (sb | 0x80000000u);
      best = ((unsigned long long)sb << 32) | (unsigned)jl;
    }
    for (int off = 32; off > 0; off >>= 1) {
      unsigned long long o = __shfl_xor(best, off, 64);
      if (o < best) best = o;
    }
    int j1 = (int)(best & 0xFFFFFFFFu);
    float m1g;
    {
      unsigned sb = (unsigned)(best >> 32);
      m1g = __uint_as_float((sb >> 31) ? (sb ^ 0x80000000u) : ~sb);
    }
    float c2 = (jl == j1) ? m2 : m1;   // global 2nd min = min excluding col j1
    for (int off = 32; off > 0; off >>= 1) c2 = fminf(c2, __shfl_xor(c2, off, 64));
    float delta = (c2 > m1g) ? (c2 - m1g) : 0.f;
    int i1 = p[j1];
    if (i1 >= 0 && delta <= 0.f) {
      // exact tie on an occupied column: leave row i free for SAP
      if (lane == 0) u[i] = c2;
      continue;
    }
#pragma unroll
    for (int w = 0; w < 5; ++w) if (lane + 64 * w == j1) v[w] -= delta;
    if (lane == 0) {
      u[i] = c2;
      p[j1] = i;
      rowUsed[i] = 1;
      if (i1 >= 0) { rowUsed[i1] = 0; queue[t] = i1; qmisc[1] = t + 1; }
    }
  }
  __syncthreads();

  // ---- shortest augmenting path (Dijkstra form) for leftover free rows ----
  for (int i = 0; i < NM; ++i) {
    if (rowUsed[i]) continue;
    float dv[5]; int usedR[5];
#pragma unroll
    for (int w = 0; w < 5; ++w) {
      int j = lane + 64 * w;
      dv[w] = INF;
      usedR[w] = (j >= NQ) ? 1 : 0;
      way[j] = -1;
    }
    float S = 0.f;
    int nr = i, j0 = -1;
    while (true) {
      float urow = u[nr];                 // unchanged during the phase
      unsigned long long best = ~0ull;
#pragma unroll
      for (int w = 0; w < 5; ++w) {
        if (!usedR[w]) {
          int j = lane + 64 * w;
          float cand = S + cost[nr * CTP + j] - urow - v[w];
          if (cand < dv[w]) { dv[w] = cand; way[j] = j0; }
          unsigned sb = __float_as_uint(dv[w]);
          sb = (sb >> 31) ? ~sb : (sb | 0x80000000u);
          unsigned long long key = ((unsigned long long)sb << 32) | (unsigned)j;
          if (key < best) best = key;
        }
      }
      for (int off = 32; off > 0; off >>= 1) {
        unsigned long long o = __shfl_xor(best, off, 64);
        if (o < best) best = o;
      }
      int j1 = (int)(best & 0xFFFFFFFFu);
      {
        unsigned sb = (unsigned)(best >> 32);
        S = __uint_as_float((sb >> 31) ? (sb ^ 0x80000000u) : ~sb);
      }
#pragma unroll
      for (int w = 0; w < 5; ++w) if (lane + 64 * w == j1) usedR[w] = 1;
      j0 = j1;
      int nr2 = p[j1];
      if (nr2 < 0) break;
      nr = nr2;
    }
    // phase-end dual updates (reads p BEFORE augmentation rewires it)
#pragma unroll
    for (int w = 0; w < 5; ++w) {
      int j = lane + 64 * w;
      if (j < NQ && usedR[w]) {
        float amt = S - dv[w];            // = sum of deltas since j joined
        v[w] -= amt;
        int pj = p[j];
        if (pj >= 0) u[pj] += amt;        // distinct rows across lanes
      }
    }
    if (lane == 0) u[i] += S;
    __syncthreads();
    if (lane == 0) {                      // backtrack augmenting path
      int j = j0;
      while (j != -1) {
        int jp = way[j];
        p[j] = (jp != -1) ? p[jp] : i;
        j = jp;
      }
      rowUsed[i] = 1;
    }
    __syncthreads();
  }

  // ---- parallel emit: sorted (pred, gt) pairs via ballot prefix ----
  {
    float* po = out + NB * NQ * NM + b * NM;
    float* go = out + NB * NQ * NM + NB * NM + b * NM;
    int base = 0;
#pragma unroll
    for (int w = 0; w < 5; ++w) {
      int j = lane + 64 * w;
      int pj = (j < NQ) ? p[j] : -1;
      unsigned long long mask = __ballot(pj >= 0);
      if (pj >= 0) {
        int pos = base + (int)__popcll(mask & ((1ull << lane) - 1ull));
        po[pos] = (float)j;
        go[pos] = (float)pj;
      }
      base += (int)__popcll(mask);
    }
  }
}

extern "C" void kernel_launch(void* const* d_in, const int* in_sizes, int n_in,
                              void* d_out, int out_size, void* d_ws, size_t ws_size,
                              hipStream_t stream) {
  const float* logits = (const float*)d_in[0];
  const float* pboxes = (const float*)d_in[1];
  const float* pmask  = (const float*)d_in[2];
  const int*   labels = (const int*)d_in[3];
  const float* gboxes = (const float*)d_in[4];
  const float* gmask  = (const float*)d_in[5];
  float* out = (float*)d_out;
  char* ws = (char*)d_ws;

  // ws layout (bytes)
  unsigned short* pm   = (unsigned short*)(ws + 0);          //  78,643,200
  unsigned short* gmb  = (unsigned short*)(ws + 78643200);   //  26,214,400
  float* psum  = (float*)(ws + 104857600);                   //       9,600
  float* gsum  = (float*)(ws + 104867200);                   //       3,200
  float* probs = (float*)(ws + 104870400);                   //     777,600
  float* dotv  = (float*)(ws + 105648000);                   //     960,000
  float* ct    = (float*)(ws + 106608000);                   //     972,800

  hipFuncSetAttribute(reinterpret_cast<const void*>(hungarian_kernel),
                      hipFuncAttributeMaxDynamicSharedMemorySize, 127872);

  hipMemsetAsync(dotv, 0, NB * NQ * NM * sizeof(float), stream);
  hipLaunchKernelGGL(prep_kernel, dim3(NB * NQ + NB * NM), dim3(256), 0, stream,
                     pmask, gmask, pm, gmb, psum, gsum);
  hipLaunchKernelGGL(softmax_kernel, dim3(600), dim3(256), 0, stream, logits, probs);
  hipLaunchKernelGGL(dot_kernel, dim3(19, NB * NKC), dim3(64), 0, stream, pm, gmb, dotv);
  hipLaunchKernelGGL(combine_kernel, dim3((NB * NQ * NM + 255) / 256), dim3(256), 0, stream,
                     dotv, psum, gsum, probs, labels, pboxes, gboxes, out, ct);
  hipLaunchKernelGGL(hungarian_kernel, dim3(NB), dim3(64), 127872, stream, ct, out);
}

// Round 2
// 494.694 us; speedup vs baseline: 1.0605x; 1.0605x over previous
//
#include <hip/hip_runtime.h>

#define HW 16384
#define NQ 300
#define NM 100
#define NB 8
#define NC 81
#define KCH 1024   // K split into 16 chunks
#define NKC 16
#define CTP 304    // padded leading dim for transposed cost

typedef __attribute__((ext_vector_type(8))) short frag8;
typedef __attribute__((ext_vector_type(4))) float float4v;
typedef __attribute__((ext_vector_type(4))) unsigned short ushort4v;

__device__ __forceinline__ unsigned short f2bf(float f) {
  union { float f; unsigned u; } c; c.f = f;
  unsigned r = c.u + 0x7FFFu + ((c.u >> 16) & 1u);
  return (unsigned short)(r >> 16);
}

// ---- prep: sigmoid(pred_masks)->bf16 + row sums; gt_masks->bf16 + row sums ----
__global__ __launch_bounds__(256) void prep_kernel(
    const float* __restrict__ pmask, const float* __restrict__ gmask,
    unsigned short* __restrict__ pm, unsigned short* __restrict__ gm,
    float* __restrict__ psum, float* __restrict__ gsum) {
  int row = blockIdx.x;            // 0..2399 = pm rows, 2400..3199 = gm rows
  int t = threadIdx.x;
  bool isP = row < NB * NQ;
  const float* srcf = isP ? (pmask + (size_t)row * HW)
                          : (gmask + (size_t)(row - NB * NQ) * HW);
  unsigned short* dst = isP ? (pm + (size_t)row * HW)
                            : (gm + (size_t)(row - NB * NQ) * HW);
  const float4v* src = (const float4v*)srcf;
  float s = 0.f;
  for (int i = t; i < HW / 4; i += 256) {
    float4v x = src[i];
    float y0, y1, y2, y3;
    if (isP) {
      y0 = 1.f / (1.f + __expf(-x.x));
      y1 = 1.f / (1.f + __expf(-x.y));
      y2 = 1.f / (1.f + __expf(-x.z));
      y3 = 1.f / (1.f + __expf(-x.w));
    } else { y0 = x.x; y1 = x.y; y2 = x.z; y3 = x.w; }
    s += (y0 + y1) + (y2 + y3);
    ushort4v o = { f2bf(y0), f2bf(y1), f2bf(y2), f2bf(y3) };
    *(ushort4v*)(dst + i * 4) = o;
  }
  for (int off = 32; off > 0; off >>= 1) s += __shfl_xor(s, off, 64);
  __shared__ float red[4];
  int wave = t >> 6, lane = t & 63;
  if (lane == 0) red[wave] = s;
  __syncthreads();
  if (t == 0) {
    float tot = (red[0] + red[1]) + (red[2] + red[3]);
    if (isP) psum[row] = tot; else gsum[row - NB * NQ] = tot;
  }
}

// ---- softmax over 81 classes, one wave per (b,q) row ----
__global__ __launch_bounds__(256) void softmax_kernel(
    const float* __restrict__ logits, float* __restrict__ probs) {
  int wave = threadIdx.x >> 6, lane = threadIdx.x & 63;
  int row = blockIdx.x * 4 + wave;          // < 2400 (grid=600)
  const float* in = logits + (size_t)row * NC;
  float x0 = (lane < NC) ? in[lane] : -1e30f;
  float x1 = (lane + 64 < NC) ? in[lane + 64] : -1e30f;
  float mx = fmaxf(x0, x1);
  for (int off = 32; off > 0; off >>= 1) mx = fmaxf(mx, __shfl_xor(mx, off, 64));
  float e0 = (lane < NC) ? __expf(x0 - mx) : 0.f;
  float e1 = (lane + 64 < NC) ? __expf(x1 - mx) : 0.f;
  float s = e0 + e1;
  for (int off = 32; off > 0; off >>= 1) s += __shfl_xor(s, off, 64);
  float inv = 1.f / s;
  if (lane < NC) probs[(size_t)row * NC + lane] = e0 * inv;
  if (lane + 64 < NC) probs[(size_t)row * NC + lane + 64] = e1 * inv;
}

// ---- bf16 MFMA batched GEMM: dot[b,q,m] accumulated via fp32 atomics ----
// One wave per (16-q tile, b, kc of 16); 2432 waves => ~9.5 waves/CU.
__global__ __launch_bounds__(64) void dot_kernel(
    const unsigned short* __restrict__ pm, const unsigned short* __restrict__ gm,
    float* __restrict__ dotv) {
  int qt = blockIdx.x;                      // 0..18 (16-q tiles)
  int b = blockIdx.y >> 4, kc = blockIdx.y & 15;
  int lane = threadIdx.x;
  int q0 = qt * 16;
  int row_a = q0 + (lane & 15);
  int ra = (row_a < NQ) ? row_a : NQ - 1;   // clamp; clamped rows never stored
  int koff = (lane >> 4) * 8;
  const unsigned short* pA = pm + ((size_t)b * NQ + ra) * HW + kc * KCH + koff;
  const unsigned short* pB0 = gm + (size_t)b * NM * HW + kc * KCH + koff;
  const unsigned short* pB[7];
#pragma unroll
  for (int mt = 0; mt < 7; ++mt) {
    int row_b = mt * 16 + (lane & 15);
    int rb = (row_b < NM) ? row_b : NM - 1;
    pB[mt] = pB0 + (size_t)rb * HW;
  }
  float4v acc[7];
#pragma unroll
  for (int mt = 0; mt < 7; ++mt) acc[mt] = (float4v){0.f, 0.f, 0.f, 0.f};
#pragma unroll 2
  for (int k = 0; k < KCH; k += 32) {
    frag8 a = *(const frag8*)(pA + k);
#pragma unroll
    for (int mt = 0; mt < 7; ++mt) {
      frag8 bb = *(const frag8*)(pB[mt] + k);
      acc[mt] = __builtin_amdgcn_mfma_f32_16x16x32_bf16(a, bb, acc[mt], 0, 0, 0);
    }
  }
  // C/D layout: col = lane&15 (m), row = (lane>>4)*4 + r (q)
#pragma unroll
  for (int mt = 0; mt < 7; ++mt) {
    int cm = mt * 16 + (lane & 15);
    if (cm < NM) {
#pragma unroll
      for (int r = 0; r < 4; ++r) {
        int cq = q0 + (lane >> 4) * 4 + r;
        if (cq < NQ)
          unsafeAtomicAdd(&dotv[((size_t)b * NQ + cq) * NM + cm], acc[mt][r]);
      }
    }
  }
}

// ---- combine all cost terms -> C (d_out) and transposed copy CT (ws) ----
__global__ __launch_bounds__(256) void combine_kernel(
    const float* __restrict__ dotv, const float* __restrict__ psum,
    const float* __restrict__ gsum, const float* __restrict__ probs,
    const int* __restrict__ labels, const float* __restrict__ pboxes,
    const float* __restrict__ gboxes, float* __restrict__ outC,
    float* __restrict__ ct) {
  int idx = blockIdx.x * 256 + threadIdx.x;
  if (idx >= NB * NQ * NM) return;
  int b = idx / (NQ * NM);
  int r = idx - b * (NQ * NM);
  int q = r / NM;
  int m = r - q * NM;
  float num = 2.f * dotv[idx];
  float den = psum[b * NQ + q] + gsum[b * NM + m];
  float cmask = 1.f - num / (den + 1e-6f);
  int lab = labels[b * NM + m];
  float cclass = -probs[((size_t)b * NQ + q) * NC + lab];
  const float* pb = pboxes + ((size_t)b * NQ + q) * 4;
  const float* gb = gboxes + ((size_t)b * NM + m) * 4;
  float p0 = pb[0], p1 = pb[1], p2 = pb[2], p3 = pb[3];
  float g0 = gb[0], g1 = gb[1], g2 = gb[2], g3 = gb[3];
  float cbbox = fabsf(p0 - g0) + fabsf(p1 - g1) + fabsf(p2 - g2) + fabsf(p3 - g3);
  float iw = fmaxf(fminf(p2, g2) - fmaxf(p0, g0), 0.f);
  float ih = fmaxf(fminf(p3, g3) - fmaxf(p1, g1), 0.f);
  float inter = iw * ih;
  float a1 = (p2 - p0) * (p3 - p1), a2 = (g2 - g0) * (g3 - g1);
  float uni = a1 + a2 - inter;
  float iou = inter / (uni + 1e-6f);
  float aw = fmaxf(fmaxf(p2, g2) - fminf(p0, g0), 0.f);
  float ah = fmaxf(fmaxf(p3, g3) - fminf(p1, g1), 0.f);
  float am = aw * ah;
  float giou = iou - (am - uni) / (am + 1e-6f);
  float C = cclass + 5.f * (cbbox - giou) + 2.f * cmask;
  outC[idx] = C;
  ct[((size_t)b * NM + m) * CTP + q] = C;   // transposed for the solver
}

// f32 full-wave min via DPP (row_shr 1/2/4/8 + bcast15/31 -> lane 63),
// broadcast back through an SGPR. ~6 dependent VALU ops + 1 readlane,
// replaces 6x 64-bit __shfl_xor (12 dependent ds_bpermute round-trips).
__device__ __forceinline__ float wave_fmin_bcast(float x) {
  int t;
  t = __builtin_amdgcn_update_dpp(__float_as_int(x), __float_as_int(x), 0x111, 0xf, 0xf, false);
  x = fminf(x, __int_as_float(t));  // row_shr:1
  t = __builtin_amdgcn_update_dpp(__float_as_int(x), __float_as_int(x), 0x112, 0xf, 0xf, false);
  x = fminf(x, __int_as_float(t));  // row_shr:2
  t = __builtin_amdgcn_update_dpp(__float_as_int(x), __float_as_int(x), 0x114, 0xf, 0xf, false);
  x = fminf(x, __int_as_float(t));  // row_shr:4
  t = __builtin_amdgcn_update_dpp(__float_as_int(x), __float_as_int(x), 0x118, 0xf, 0xf, false);
  x = fminf(x, __int_as_float(t));  // row_shr:8
  t = __builtin_amdgcn_update_dpp(__float_as_int(x), __float_as_int(x), 0x142, 0xf, 0xf, false);
  x = fminf(x, __int_as_float(t));  // row_bcast:15
  t = __builtin_amdgcn_update_dpp(__float_as_int(x), __float_as_int(x), 0x143, 0xf, 0xf, false);
  x = fminf(x, __int_as_float(t));  // row_bcast:31
  return __int_as_float(__builtin_amdgcn_readlane(__float_as_int(x), 63));
}

// ---- Jonker-Volgenant on cost.T [100 x 300], one wave per batch ----
// v3 = v2 algorithm (greedy init + budgeted augmenting row reduction +
// Dijkstra-form SAP; proven passing) with the serial chain de-latencied:
//  * all argmin reduces: DPP f32 wave-min + ballot-scan for the column.
//    Tie-break identical to the old 64-bit packed key (lowest j achieving
//    the min: w-blocks are ascending j-ranges, ctz gives lowest lane).
//  * SAP phases read p[] and u[] from register mirrors via v_readlane
//    (p/u/v are FROZEN during a Dijkstra phase; mirrors refresh per phase).
//  * free rows collected once into a list (ballot prefix) -> outer loop
//    touches only truly-free rows (SAP never frees an assigned row).
extern __shared__ char hsmem[];
__global__ __launch_bounds__(64) void hungarian_kernel(
    const float* __restrict__ ct, float* __restrict__ out) {
  float* cost   = (float*)hsmem;                     // 100*304 f32 = 121600 B
  float* u      = (float*)(hsmem + 121600);          // 100 f32
  int*   p      = (int*)(hsmem + 122000);            // 320 int (col -> row)
  int*   way    = (int*)(hsmem + 123280);            // 320 int
  int*   colOwn = (int*)(hsmem + 124560);            // 320 int (reused: flist)
  int*   rowUsed= (int*)(hsmem + 125840);            // 100 int
  int*   queue  = (int*)(hsmem + 126240);            // 400 int
  int*   qmisc  = (int*)(hsmem + 127840);            // 8 int: [0]=head [1]=tail
  int*   flist  = colOwn;                            // free-row list (<=100)
  const int b = blockIdx.x;
  const int lane = threadIdx.x;
  const float INF = __builtin_inff();

  // vectorized cost load: 121600 B as float4 (CTP=304 keeps rows 16B-aligned)
  {
    const float4v* a4 = (const float4v*)(ct + (size_t)b * NM * CTP);
    float4v* c4 = (float4v*)cost;
    for (int i = lane; i < NM * CTP / 4; i += 64) c4[i] = a4[i];
  }
#pragma unroll
  for (int w = 0; w < 5; ++w) {
    p[lane + 64 * w] = -1;
    colOwn[lane + 64 * w] = 0x7fffffff;
  }
  if (lane == 0) { qmisc[0] = 0; qmisc[1] = 0; }
  float v[5];
#pragma unroll
  for (int w = 0; w < 5; ++w) v[w] = 0.f;
  __syncthreads();

  // ---- row reduction: u[i] = min_j cost[i][j]; remember argmin col ----
  int rarg0 = 0, rarg1 = 0;
  {
    int i = lane;                 // rows 0..63
    float mv = INF; int cj = 0;
    for (int j = 0; j < NQ; ++j) {
      float c = cost[i * CTP + j];
      if (c < mv) { mv = c; cj = j; }
    }
    u[i] = mv; rarg0 = cj;
  }
  if (lane < NM - 64) {           // rows 64..99
    int i = lane + 64;
    float mv = INF; int cj = 0;
    for (int j = 0; j < NQ; ++j) {
      float c = cost[i * CTP + j];
      if (c < mv) { mv = c; cj = j; }
    }
    u[i] = mv; rarg1 = cj;
  }
  // ---- parallel greedy: lowest row index wins its argmin column ----
  atomicMin(&colOwn[rarg0], lane);
  if (lane < NM - 64) atomicMin(&colOwn[rarg1], lane + 64);
  __syncthreads();
  int free0 = 0, free1 = 0;
  {
    bool won = (colOwn[rarg0] == lane);
    if (won) p[rarg0] = lane;
    rowUsed[lane] = won ? 1 : 0;
    free0 = won ? 0 : 1;
  }
  if (lane < NM - 64) {
    bool won = (colOwn[rarg1] == lane + 64);
    if (won) p[rarg1] = lane + 64;
    rowUsed[lane + 64] = won ? 1 : 0;
    free1 = won ? 0 : 1;
  }
  // deterministic free-row queue, ascending row index
  {
    unsigned long long m0 = __ballot(free0 != 0);
    if (free0) queue[__popcll(m0 & ((1ull << lane) - 1ull))] = lane;
    int base = (int)__popcll(m0);
    unsigned long long m1 = __ballot(free1 != 0);
    if (free1) queue[base + (int)__popcll(m1 & ((1ull << lane) - 1ull))] = lane + 64;
    base += (int)__popcll(m1);
    if (lane == 0) qmisc[1] = base;
  }

  // ---- augmenting row reduction (budgeted) ----
  int pops = 0;
  while (true) {
    __syncthreads();
    int h = qmisc[0], t = qmisc[1];
    if (h >= t || pops >= 192) break;
    int i = queue[h];
    ++pops;
    if (lane == 0) qmisc[0] = h + 1;
    // wave-parallel scan: keep per-w reduced costs + per-lane min1/min2
    float tv[5];
    float m1 = INF, m2 = INF;
#pragma unroll
    for (int w = 0; w < 5; ++w) {
      int j = lane + 64 * w;
      float tt = (j < NQ) ? (cost[i * CTP + j] - v[w]) : INF;
      tv[w] = tt;
      if (tt < m1) { m2 = m1; m1 = tt; } else if (tt < m2) m2 = tt;
    }
    float m1g = wave_fmin_bcast(m1);
    int j1 = -1;
#pragma unroll
    for (int w = 0; w < 5; ++w) {
      unsigned long long mk = __ballot(tv[w] == m1g);
      if (j1 < 0 && mk) j1 = (int)__builtin_ctzll(mk) + 64 * w;
    }
    // global 2nd min = min over all cols except j1
    float c2c = INF;
#pragma unroll
    for (int w = 0; w < 5; ++w)
      if (lane + 64 * w != j1) c2c = fminf(c2c, tv[w]);
    float c2 = wave_fmin_bcast(c2c);
    float delta = (c2 > m1g) ? (c2 - m1g) : 0.f;
    int i1 = p[j1];
    if (i1 >= 0 && delta <= 0.f) {
      // exact tie on an occupied column: leave row i free for SAP
      if (lane == 0) u[i] = c2;
      continue;
    }
#pragma unroll
    for (int w = 0; w < 5; ++w) if (lane + 64 * w == j1) v[w] -= delta;
    if (lane == 0) {
      u[i] = c2;
      p[j1] = i;
      rowUsed[i] = 1;
      if (i1 >= 0) { rowUsed[i1] = 0; queue[t] = i1; qmisc[1] = t + 1; }
    }
  }
  __syncthreads();

  // ---- collect free rows once (SAP never frees an assigned row) ----
  int nfree;
  {
    int r0 = rowUsed[lane];
    int r1 = (lane < NM - 64) ? rowUsed[lane + 64] : 1;
    unsigned long long m0 = __ballot(r0 == 0);
    if (!r0) flist[__popcll(m0 & ((1ull << lane) - 1ull))] = lane;
    int base = (int)__popcll(m0);
    unsigned long long m1 = __ballot(r1 == 0);
    if (!r1) flist[base + (int)__popcll(m1 & ((1ull << lane) - 1ull))] = lane + 64;
    nfree = base + (int)__popcll(m1);
  }
  __syncthreads();

  // register mirrors of p[] and u[] (valid while frozen within a SAP phase)
  int pr0, pr1, pr2, pr3, pr4;
  float ur0, ur1;
  pr0 = p[lane]; pr1 = p[lane + 64]; pr2 = p[lane + 128];
  pr3 = p[lane + 192]; pr4 = p[lane + 256];
  ur0 = u[lane];
  ur1 = (lane < NM - 64) ? u[lane + 64] : 0.f;

  // ---- shortest augmenting path (Dijkstra form) for leftover free rows ----
  for (int fi = 0; fi < nfree; ++fi) {
    int i = flist[fi];
    float dv[5]; int usedR[5];
#pragma unroll
    for (int w = 0; w < 5; ++w) {
      int j = lane + 64 * w;
      dv[w] = INF;
      usedR[w] = (j >= NQ) ? 1 : 0;
      way[j] = -1;
    }
    float S = 0.f;
    int nr = i, j0 = -1;
    while (true) {
      // u[nr] via readlane from mirror (uniform nr)
      float urow;
      {
        int bits = (nr < 64)
            ? __builtin_amdgcn_readlane(__float_as_int(ur0), nr & 63)
            : __builtin_amdgcn_readlane(__float_as_int(ur1), nr & 63);
        urow = __int_as_float(bits);
      }
      int base = nr * CTP;
      float c0 = cost[base + lane];
      float c1 = cost[base + lane + 64];
      float c2_ = cost[base + lane + 128];
      float c3 = cost[base + lane + 192];
      float c4 = cost[base + lane + 256];   // j>=300 lanes: discarded (usedR)
      float cr[5] = {c0, c1, c2_, c3, c4};
      float cmin = INF;
#pragma unroll
      for (int w = 0; w < 5; ++w) {
        if (!usedR[w]) {
          float cand = S + cr[w] - urow - v[w];
          if (cand < dv[w]) { dv[w] = cand; way[lane + 64 * w] = j0; }
          cmin = fminf(cmin, dv[w]);
        }
      }
      float m = wave_fmin_bcast(cmin);
      int j1 = -1;
#pragma unroll
      for (int w = 0; w < 5; ++w) {
        unsigned long long mk = __ballot(!usedR[w] && dv[w] == m);
        if (j1 < 0 && mk) j1 = (int)__builtin_ctzll(mk) + 64 * w;
      }
      S = m;
#pragma unroll
      for (int w = 0; w < 5; ++w) if (lane + 64 * w == j1) usedR[w] = 1;
      j0 = j1;
      // p[j1] via readlane from mirror (uniform j1; p frozen in-phase)
      int nr2;
      {
        int sl = j1 >> 6, ln = j1 & 63;
        if (sl == 0)      nr2 = __builtin_amdgcn_readlane(pr0, ln);
        else if (sl == 1) nr2 = __builtin_amdgcn_readlane(pr1, ln);
        else if (sl == 2) nr2 = __builtin_amdgcn_readlane(pr2, ln);
        else if (sl == 3) nr2 = __builtin_amdgcn_readlane(pr3, ln);
        else              nr2 = __builtin_amdgcn_readlane(pr4, ln);
      }
      if (nr2 < 0) break;
      nr = nr2;
    }
    // phase-end dual updates (mirror pr* is pre-augmentation p — required)
#pragma unroll
    for (int w = 0; w < 5; ++w) {
      int j = lane + 64 * w;
      if (j < NQ && usedR[w]) {
        float amt = S - dv[w];            // = sum of deltas since j joined
        v[w] -= amt;
        int pj = (w == 0) ? pr0 : (w == 1) ? pr1 : (w == 2) ? pr2
               : (w == 3) ? pr3 : pr4;
        if (pj >= 0) u[pj] += amt;        // distinct rows across lanes
      }
    }
    if (lane == 0) u[i] += S;
    __syncthreads();
    if (lane == 0) {                      // backtrack augmenting path
      int j = j0;
      while (j != -1) {
        int jp = way[j];
        p[j] = (jp != -1) ? p[jp] : i;
        j = jp;
      }
    }
    __syncthreads();
    // refresh mirrors (p rewired by backtrack, u updated above)
    pr0 = p[lane]; pr1 = p[lane + 64]; pr2 = p[lane + 128];
    pr3 = p[lane + 192]; pr4 = p[lane + 256];
    ur0 = u[lane];
    ur1 = (lane < NM - 64) ? u[lane + 64] : 0.f;
  }

  // ---- parallel emit: sorted (pred, gt) pairs via ballot prefix ----
  {
    float* po = out + NB * NQ * NM + b * NM;
    float* go = out + NB * NQ * NM + NB * NM + b * NM;
    int base = 0;
#pragma unroll
    for (int w = 0; w < 5; ++w) {
      int j = lane + 64 * w;
      int pj = (j < NQ) ? p[j] : -1;
      unsigned long long mask = __ballot(pj >= 0);
      if (pj >= 0) {
        int pos = base + (int)__popcll(mask & ((1ull << lane) - 1ull));
        po[pos] = (float)j;
        go[pos] = (float)pj;
      }
      base += (int)__popcll(mask);
    }
  }
}

extern "C" void kernel_launch(void* const* d_in, const int* in_sizes, int n_in,
                              void* d_out, int out_size, void* d_ws, size_t ws_size,
                              hipStream_t stream) {
  const float* logits = (const float*)d_in[0];
  const float* pboxes = (const float*)d_in[1];
  const float* pmask  = (const float*)d_in[2];
  const int*   labels = (const int*)d_in[3];
  const float* gboxes = (const float*)d_in[4];
  const float* gmask  = (const float*)d_in[5];
  float* out = (float*)d_out;
  char* ws = (char*)d_ws;

  // ws layout (bytes)
  unsigned short* pm   = (unsigned short*)(ws + 0);          //  78,643,200
  unsigned short* gmb  = (unsigned short*)(ws + 78643200);   //  26,214,400
  float* psum  = (float*)(ws + 104857600);                   //       9,600
  float* gsum  = (float*)(ws + 104867200);                   //       3,200
  float* probs = (float*)(ws + 104870400);                   //     777,600
  float* dotv  = (float*)(ws + 105648000);                   //     960,000
  float* ct    = (float*)(ws + 106608000);                   //     972,800

  hipFuncSetAttribute(reinterpret_cast<const void*>(hungarian_kernel),
                      hipFuncAttributeMaxDynamicSharedMemorySize, 127872);

  hipMemsetAsync(dotv, 0, NB * NQ * NM * sizeof(float), stream);
  hipLaunchKernelGGL(prep_kernel, dim3(NB * NQ + NB * NM), dim3(256), 0, stream,
                     pmask, gmask, pm, gmb, psum, gsum);
  hipLaunchKernelGGL(softmax_kernel, dim3(600), dim3(256), 0, stream, logits, probs);
  hipLaunchKernelGGL(dot_kernel, dim3(19, NB * NKC), dim3(64), 0, stream, pm, gmb, dotv);
  hipLaunchKernelGGL(combine_kernel, dim3((NB * NQ * NM + 255) / 256), dim3(256), 0, stream,
                     dotv, psum, gsum, probs, labels, pboxes, gboxes, out, ct);
  hipLaunchKernelGGL(hungarian_kernel, dim3(NB), dim3(64), 127872, stream, ct, out);
}